// Round 12
// baseline (96.149 us; speedup 1.0000x reference)
//
#include <hip/hip_runtime.h>
#include <hip/hip_bf16.h>
#include <math.h>

#define N_NODES 20000
#define N_EDGES 320000
#define HIDDEN 64
#define HEADS 4
#define HC 256              // HEADS*HIDDEN
#define D_INNER 256
#define NEG_SLOPE 0.2f
#define BN_EPS 1e-5f
#define MAXDEG 64           // Poisson(16) max load over 20000 bins ~40; P(>64) ~ 1e-19
#define NZERO (N_NODES + 2048)   // cursor + 8-replica stat banks
#define NB_LIN 626          // 2 * ceil(20000/64)
#define NB_FILL 1250        // 320000/256

typedef __attribute__((ext_vector_type(8))) short short8;
typedef __attribute__((ext_vector_type(4))) float f32x4;

__device__ __forceinline__ float bf2f(unsigned short u) {
    unsigned x = ((unsigned)u) << 16;
    return __uint_as_float(x);
}
__device__ __forceinline__ unsigned short f2bf(float f) {
    __hip_bfloat16 b = __float2bfloat16(f);
    return *reinterpret_cast<unsigned short*>(&b);
}
__device__ __forceinline__ void cvt8(uint4 u, float* f) {
    f[0] = __uint_as_float(u.x << 16); f[1] = __uint_as_float(u.x & 0xFFFF0000u);
    f[2] = __uint_as_float(u.y << 16); f[3] = __uint_as_float(u.y & 0xFFFF0000u);
    f[4] = __uint_as_float(u.z << 16); f[5] = __uint_as_float(u.z & 0xFFFF0000u);
    f[6] = __uint_as_float(u.w << 16); f[7] = __uint_as_float(u.w & 0xFFFF0000u);
}
// safe gather index: perm is NOT zeroed; clamp garbage (incl. 0xAA poison) to 0
__device__ __forceinline__ int clampi(int v) {
    return ((unsigned)v < (unsigned)N_NODES) ? v : 0;
}

// ---- weight prep: bf16 transposed W1,W2,Wl,Wr + zero cursor/stats ----
__global__ __launch_bounds__(256) void k_wprep(const float* __restrict__ W1, const float* __restrict__ W2,
                                               const float* __restrict__ Wl, const float* __restrict__ Wr,
                                               unsigned short* __restrict__ W1tb, unsigned short* __restrict__ W2tb,
                                               unsigned short* __restrict__ Wlrtb,
                                               int* __restrict__ zbuf) {
    int idx = blockIdx.x * 256 + threadIdx.x;      // 256*256 = 65536 threads
    if (idx < NZERO) zbuf[idx] = 0;
    if (idx < 16384) {
        int k = idx >> 8, n = idx & 255;
        W1tb[n * 64 + k] = f2bf(W1[idx]);
    } else if (idx < 32768) {
        int j = idx - 16384;
        int k = j >> 6, n = j & 63;
        W2tb[n * 256 + k] = f2bf(W2[j]);
    } else if (idx < 49152) {
        int j = idx - 32768;
        int k = j >> 8, n = j & 255;
        Wlrtb[n * 64 + k] = f2bf(Wl[j]);
    } else {
        int j = idx - 49152;
        int k = j >> 8, n = j & 255;
        Wlrtb[16384 + n * 64 + k] = f2bf(Wr[j]);
    }
}

// ---- fused: blocks [0,NB_LIN) do MFMA x@Wl/Wr -> xlb/xrb ; rest do edge bucket fill ----
__global__ __launch_bounds__(256) void k_prep(const float* __restrict__ x,
                                              const unsigned short* __restrict__ Wlrtb,
                                              const float* __restrict__ bl, const float* __restrict__ br,
                                              unsigned short* __restrict__ xlb, unsigned short* __restrict__ xrb,
                                              const int* __restrict__ ei,
                                              int* __restrict__ cursor, int* __restrict__ perm) {
    __shared__ unsigned short sW[16384];   // 32KB [256n][64k] swizzled (linm role only)
    int t = threadIdx.x;
    if (blockIdx.x >= NB_LIN) {
        int e = (blockIdx.x - NB_LIN) * 256 + t;
        int ed = ei[N_EDGES + e];
        int slot = atomicAdd(&cursor[ed], 1);
        perm[ed * MAXDEG + slot] = ei[e];
        return;
    }
    int w = t >> 6, lane = t & 63;
    int l15 = lane & 15, lg = lane >> 4;
    int side = blockIdx.x & 1;
    int row0 = (blockIdx.x >> 1) * 64;
    const float* bias = side ? br : bl;
    unsigned short* dst = side ? xrb : xlb;
    {
        const short8* src = (const short8*)(Wlrtb + side * 16384);
#pragma unroll
        for (int it = 0; it < 8; ++it) {
            int i = it * 256 + t;
            int n = i >> 3, c = i & 7;
            *(short8*)((char*)sW + n * 128 + ((c * 16) ^ ((n & 7) << 4))) = src[i];
        }
    }
    short8 af[4][2];
#pragma unroll
    for (int mt = 0; mt < 4; ++mt) {
        int gm = row0 + mt * 16 + l15;
        bool valid = gm < N_NODES;
#pragma unroll
        for (int kk = 0; kk < 2; ++kk) {
            int k0 = kk * 32 + lg * 8;
            float4 v0 = {0.f,0.f,0.f,0.f}, v1 = {0.f,0.f,0.f,0.f};
            if (valid) {
                v0 = *(const float4*)(x + (size_t)gm * 64 + k0);
                v1 = *(const float4*)(x + (size_t)gm * 64 + k0 + 4);
            }
            short8 f;
            f[0] = (short)f2bf(v0.x); f[1] = (short)f2bf(v0.y);
            f[2] = (short)f2bf(v0.z); f[3] = (short)f2bf(v0.w);
            f[4] = (short)f2bf(v1.x); f[5] = (short)f2bf(v1.y);
            f[6] = (short)f2bf(v1.z); f[7] = (short)f2bf(v1.w);
            af[mt][kk] = f;
        }
    }
    float bv[4];
#pragma unroll
    for (int nt = 0; nt < 4; ++nt) bv[nt] = bias[w * 64 + nt * 16 + l15];
    __syncthreads();
    f32x4 zero4 = {0.f, 0.f, 0.f, 0.f};
    f32x4 acc[4][4];
#pragma unroll
    for (int mt = 0; mt < 4; ++mt)
#pragma unroll
        for (int nt = 0; nt < 4; ++nt) acc[mt][nt] = zero4;
#pragma unroll
    for (int kk = 0; kk < 2; ++kk) {
        int kb = kk * 64 + lg * 16;
        short8 bf[4];
#pragma unroll
        for (int nt = 0; nt < 4; ++nt) {
            int n = w * 64 + nt * 16 + l15;
            bf[nt] = *(const short8*)((const char*)sW + n * 128 + (kb ^ ((n & 7) << 4)));
        }
#pragma unroll
        for (int mt = 0; mt < 4; ++mt)
#pragma unroll
            for (int nt = 0; nt < 4; ++nt)
                acc[mt][nt] = __builtin_amdgcn_mfma_f32_16x16x32_bf16(af[mt][kk], bf[nt], acc[mt][nt], 0, 0, 0);
    }
#pragma unroll
    for (int mt = 0; mt < 4; ++mt)
#pragma unroll
        for (int nt = 0; nt < 4; ++nt) {
            int n = w * 64 + nt * 16 + l15;
#pragma unroll
            for (int r = 0; r < 4; ++r) {
                int gm = row0 + mt * 16 + lg * 4 + r;
                if (gm < N_NODES)
                    dst[(size_t)gm * 256 + n] = f2bf(acc[mt][nt][r] + bv[nt]);
            }
        }
}

// ---- fused GATv2 + residual + BN1 stats: 2 nodes/wave, 2 edges/iter ILP, no-max softmax ----
__global__ __launch_bounds__(256) void k_gat(const unsigned short* __restrict__ xlb,
                                             const unsigned short* __restrict__ xrb,
                                             const float* __restrict__ att,
                                             const int* __restrict__ perm,
                                             const int* __restrict__ cnt,
                                             const float* __restrict__ x,
                                             const float* __restrict__ bias,
                                             float* __restrict__ y1,
                                             float* __restrict__ gsum, float* __restrict__ gsq) {
    __shared__ float ps[8][64], pq[8][64];
    int t = threadIdx.x;
    int hw = t >> 5, l = t & 31;            // half-wave id, lane-in-half
    int node = blockIdx.x * 8 + hw;
    const uint4* xl4 = (const uint4*)xlb;
    // lane l owns flat features [l*8, l*8+8) -> head l>>3
    uint4 xru = ((const uint4*)xrb)[(size_t)node * 32 + l];
    float xr[8]; cvt8(xru, xr);
    float at[8];
    *(float4*)(at)     = *(const float4*)(att + l * 8);
    *(float4*)(at + 4) = *(const float4*)(att + l * 8 + 4);
    int deg = cnt[node];
    int mdeg = max(deg, __shfl_xor(deg, 32));
    const int* ep = perm + (size_t)node * MAXDEG;
    float d = 0.f;
    float acc[8] = {0.f,0.f,0.f,0.f,0.f,0.f,0.f,0.f};
    // indices clamped -> loads safe even where perm holds poison (w=0 there anyway)
    uint4 b0 = xl4[(size_t)clampi(ep[0]) * 32 + l];
    uint4 b1 = xl4[(size_t)clampi(ep[1]) * 32 + l];
    uint4 b2 = xl4[(size_t)clampi(ep[2]) * 32 + l];
    uint4 b3 = xl4[(size_t)clampi(ep[3]) * 32 + l];
    for (int j = 0; j < mdeg; j += 2) {
        uint4 n0 = xl4[(size_t)clampi(ep[j + 4]) * 32 + l];   // j+5 <= mdeg+3 < MAXDEG
        uint4 n1 = xl4[(size_t)clampi(ep[j + 5]) * 32 + l];
        float xl0[8], xl1[8];
        cvt8(b0, xl0); cvt8(b1, xl1);
        float sv0 = 0.f, sa0 = 0.f, sv1 = 0.f, sa1 = 0.f;
#pragma unroll
        for (int i = 0; i < 8; ++i) {
            float v0 = xl0[i] + xr[i];
            float v1 = xl1[i] + xr[i];
            sv0 = fmaf(at[i], v0, sv0);
            sa0 = fmaf(at[i], fabsf(v0), sa0);
            sv1 = fmaf(at[i], v1, sv1);
            sa1 = fmaf(at[i], fabsf(v1), sa1);
        }
        // a . lrelu(v) = 0.6 (a.v) + 0.4 (a.|v|)  for slope 0.2
        float s0 = 0.6f * sv0 + 0.4f * sa0;
        float s1 = 0.6f * sv1 + 0.4f * sa1;
        s0 += __shfl_xor(s0, 1); s1 += __shfl_xor(s1, 1);
        s0 += __shfl_xor(s0, 2); s1 += __shfl_xor(s1, 2);
        s0 += __shfl_xor(s0, 4); s1 += __shfl_xor(s1, 4);
        float w0 = (j < deg)     ? __expf(s0) : 0.f;  // scores bounded ~|7|: no-max safe
        float w1 = (j + 1 < deg) ? __expf(s1) : 0.f;
        d += w0 + w1;
#pragma unroll
        for (int i = 0; i < 8; ++i)
            acc[i] = fmaf(w0, xl0[i], fmaf(w1, xl1[i], acc[i]));
        b0 = b2; b1 = b3; b2 = n0; b3 = n1;
    }
    float inv = 1.f / fmaxf(d, 1e-16f);
#pragma unroll
    for (int i = 0; i < 8; ++i) {
        float v2 = acc[i] * inv;
        v2 += __shfl_xor(v2, 8);             // combine 4 heads (same channel slice)
        v2 += __shfl_xor(v2, 16);
        acc[i] = v2;
    }
    if (l < 8) {
        float4 xv0 = *(const float4*)(x + (size_t)node * 64 + l * 8);
        float4 xv1 = *(const float4*)(x + (size_t)node * 64 + l * 8 + 4);
        float4 bv0 = *(const float4*)(bias + l * 8);
        float4 bv1 = *(const float4*)(bias + l * 8 + 4);
        float4 y0, y1v;
        y0.x = xv0.x + 0.25f * acc[0] + bv0.x;
        y0.y = xv0.y + 0.25f * acc[1] + bv0.y;
        y0.z = xv0.z + 0.25f * acc[2] + bv0.z;
        y0.w = xv0.w + 0.25f * acc[3] + bv0.w;
        y1v.x = xv1.x + 0.25f * acc[4] + bv1.x;
        y1v.y = xv1.y + 0.25f * acc[5] + bv1.y;
        y1v.z = xv1.z + 0.25f * acc[6] + bv1.z;
        y1v.w = xv1.w + 0.25f * acc[7] + bv1.w;
        *(float4*)(y1 + (size_t)node * 64 + l * 8) = y0;
        *(float4*)(y1 + (size_t)node * 64 + l * 8 + 4) = y1v;
        int c = l * 8;
        ps[hw][c+0] = y0.x; ps[hw][c+1] = y0.y; ps[hw][c+2] = y0.z; ps[hw][c+3] = y0.w;
        ps[hw][c+4] = y1v.x; ps[hw][c+5] = y1v.y; ps[hw][c+6] = y1v.z; ps[hw][c+7] = y1v.w;
        pq[hw][c+0] = y0.x*y0.x; pq[hw][c+1] = y0.y*y0.y; pq[hw][c+2] = y0.z*y0.z; pq[hw][c+3] = y0.w*y0.w;
        pq[hw][c+4] = y1v.x*y1v.x; pq[hw][c+5] = y1v.y*y1v.y; pq[hw][c+6] = y1v.z*y1v.z; pq[hw][c+7] = y1v.w*y1v.w;
    }
    __syncthreads();
    if (t < 64) {
        float s = 0.f, q = 0.f;
#pragma unroll
        for (int r = 0; r < 8; ++r) { s += ps[r][t]; q += pq[r][t]; }
        int rb = blockIdx.x & 7;
        atomicAdd(&gsum[rb * 64 + t], s);
        atomicAdd(&gsq [rb * 64 + t], q);
    }
}

// ---- FFN via MFMA + inline BN1 coef + BN2 partial stats (GEMM2 B direct from global/L2) ----
__global__ __launch_bounds__(256) void k_ffn(const float* __restrict__ y1,
                                             const float* __restrict__ s1, const float* __restrict__ q1,
                                             const float* __restrict__ gamma1, const float* __restrict__ beta1,
                                             const unsigned short* __restrict__ W1tb, const float* __restrict__ b1,
                                             const unsigned short* __restrict__ W2tb, const float* __restrict__ b2,
                                             float* __restrict__ out,
                                             float* __restrict__ gsum2, float* __restrict__ gsq2) {
    __shared__ unsigned short sW[16384];   // 32KB: W1t
    __shared__ unsigned short sH[16384];   // 32KB: relu hidden, bf16 [64][256]
    __shared__ __align__(16) float sA1[64], sC1[64];
    int t = threadIdx.x;
    int w = t >> 6, lane = t & 63;
    int l15 = lane & 15, lg = lane >> 4;
    int blk = blockIdx.x;

    {
        const short8* src = (const short8*)W1tb;
#pragma unroll
        for (int it = 0; it < 8; ++it) {
            int i = it * 256 + t;
            int n = i >> 3, c = i & 7;
            *(short8*)((char*)sW + n * 128 + ((c * 16) ^ ((n & 7) << 4))) = src[i];
        }
    }
    if (t < 64) {
        float s = 0.f, q = 0.f;
#pragma unroll
        for (int r = 0; r < 8; ++r) { s += s1[r * 64 + t]; q += q1[r * 64 + t]; }
        float mu = s * (1.0f / N_NODES);
        float var = fmaxf(q * (1.0f / N_NODES) - mu * mu, 0.f);
        float av = gamma1[t] * rsqrtf(var + BN_EPS);
        sA1[t] = av; sC1[t] = beta1[t] - mu * av;
    }
    __syncthreads();

    float4 a1k[2][2], c1k[2][2];
#pragma unroll
    for (int kk = 0; kk < 2; ++kk) {
        int k0 = kk * 32 + lg * 8;
        a1k[kk][0] = *(const float4*)(sA1 + k0); a1k[kk][1] = *(const float4*)(sA1 + k0 + 4);
        c1k[kk][0] = *(const float4*)(sC1 + k0); c1k[kk][1] = *(const float4*)(sC1 + k0 + 4);
    }
    short8 af[4][2];
#pragma unroll
    for (int mt = 0; mt < 4; ++mt) {
        int gm = blk * 64 + mt * 16 + l15;
        bool valid = gm < N_NODES;
#pragma unroll
        for (int kk = 0; kk < 2; ++kk) {
            int k0 = kk * 32 + lg * 8;
            float4 v0 = {0.f,0.f,0.f,0.f}, v1 = {0.f,0.f,0.f,0.f};
            if (valid) {
                v0 = *(const float4*)(y1 + (size_t)gm * 64 + k0);
                v1 = *(const float4*)(y1 + (size_t)gm * 64 + k0 + 4);
            }
            short8 f;
            f[0] = (short)f2bf(fmaf(a1k[kk][0].x, v0.x, c1k[kk][0].x));
            f[1] = (short)f2bf(fmaf(a1k[kk][0].y, v0.y, c1k[kk][0].y));
            f[2] = (short)f2bf(fmaf(a1k[kk][0].z, v0.z, c1k[kk][0].z));
            f[3] = (short)f2bf(fmaf(a1k[kk][0].w, v0.w, c1k[kk][0].w));
            f[4] = (short)f2bf(fmaf(a1k[kk][1].x, v1.x, c1k[kk][1].x));
            f[5] = (short)f2bf(fmaf(a1k[kk][1].y, v1.y, c1k[kk][1].y));
            f[6] = (short)f2bf(fmaf(a1k[kk][1].z, v1.z, c1k[kk][1].z));
            f[7] = (short)f2bf(fmaf(a1k[kk][1].w, v1.w, c1k[kk][1].w));
            af[mt][kk] = f;
        }
    }
    float b1v[4];
#pragma unroll
    for (int nt = 0; nt < 4; ++nt) b1v[nt] = b1[w * 64 + nt * 16 + l15];

    f32x4 zero4 = {0.f, 0.f, 0.f, 0.f};
    f32x4 acc[4][4];
#pragma unroll
    for (int mt = 0; mt < 4; ++mt)
#pragma unroll
        for (int nt = 0; nt < 4; ++nt) acc[mt][nt] = zero4;
#pragma unroll
    for (int kk = 0; kk < 2; ++kk) {
        int kb = kk * 64 + lg * 16;
        short8 bf[4];
#pragma unroll
        for (int nt = 0; nt < 4; ++nt) {
            int n = w * 64 + nt * 16 + l15;
            bf[nt] = *(const short8*)((const char*)sW + n * 128 + (kb ^ ((n & 7) << 4)));
        }
#pragma unroll
        for (int mt = 0; mt < 4; ++mt)
#pragma unroll
            for (int nt = 0; nt < 4; ++nt)
                acc[mt][nt] = __builtin_amdgcn_mfma_f32_16x16x32_bf16(af[mt][kk], bf[nt], acc[mt][nt], 0, 0, 0);
    }

    // H = relu(C1 + b1) -> sH bf16 [m][n] swizzled (single barrier; no W2 restage)
#pragma unroll
    for (int mt = 0; mt < 4; ++mt)
#pragma unroll
        for (int nt = 0; nt < 4; ++nt) {
            int n = w * 64 + nt * 16 + l15;
#pragma unroll
            for (int r = 0; r < 4; ++r) {
                int m = mt * 16 + lg * 4 + r;
                float h = fmaxf(acc[mt][nt][r] + b1v[nt], 0.f);
                *(unsigned short*)((char*)sH + m * 512 + ((n * 2) ^ ((m & 7) << 4))) = f2bf(h);
            }
        }
    __syncthreads();

    // GEMM2: C2[64 x 64] = H[64x256] x W2[256x64]; B straight from global (L2-hot 32KB)
    f32x4 acc2[4];
#pragma unroll
    for (int nt = 0; nt < 4; ++nt) acc2[nt] = zero4;
#pragma unroll
    for (int kk = 0; kk < 8; ++kk) {
        int kb = kk * 64 + lg * 16;            // BYTE offset within a 512B row
        int m = w * 16 + l15;
        short8 a2 = *(const short8*)((const char*)sH + m * 512 + (kb ^ ((m & 7) << 4)));
#pragma unroll
        for (int nt = 0; nt < 4; ++nt) {
            int n = nt * 16 + l15;
            short8 b2f = *(const short8*)(W2tb + n * 256 + (kb >> 1));   // ELEMENT offset = kb/2
            acc2[nt] = __builtin_amdgcn_mfma_f32_16x16x32_bf16(a2, b2f, acc2[nt], 0, 0, 0);
        }
    }

    float b2v[4], a1n[4], c1n[4], ssum[4] = {0.f,0.f,0.f,0.f}, ssq[4] = {0.f,0.f,0.f,0.f};
#pragma unroll
    for (int nt = 0; nt < 4; ++nt) {
        int n = nt * 16 + l15;
        b2v[nt] = b2[n]; a1n[nt] = sA1[n]; c1n[nt] = sC1[n];
    }
#pragma unroll
    for (int nt = 0; nt < 4; ++nt) {
        int n = nt * 16 + l15;
#pragma unroll
        for (int r = 0; r < 4; ++r) {
            int gm = blk * 64 + w * 16 + lg * 4 + r;
            if (gm < N_NODES) {
                float v = acc2[nt][r] + b2v[nt] + fmaf(a1n[nt], y1[(size_t)gm * 64 + n], c1n[nt]);
                out[(size_t)gm * 64 + n] = v;
                ssum[nt] += v; ssq[nt] += v * v;
            }
        }
    }
    float* fs = (float*)sW;     // last sW read was in GEMM1, before the sH barrier
#pragma unroll
    for (int nt = 0; nt < 4; ++nt) {
        float ss = ssum[nt], qq = ssq[nt];
        ss += __shfl_xor(ss, 16); ss += __shfl_xor(ss, 32);
        qq += __shfl_xor(qq, 16); qq += __shfl_xor(qq, 32);
        if (lg == 0) {
            int n = nt * 16 + l15;
            fs[w * 64 + n] = ss;
            fs[256 + w * 64 + n] = qq;
        }
    }
    __syncthreads();
    if (t < 64) {
        int r = blk & 7;
        atomicAdd(&gsum2[r * 64 + t], fs[t] + fs[64 + t] + fs[128 + t] + fs[192 + t]);
        atomicAdd(&gsq2 [r * 64 + t], fs[256 + t] + fs[320 + t] + fs[384 + t] + fs[448 + t]);
    }
}

// ---- apply BN2 in-place, float4-vectorized ----
__global__ __launch_bounds__(256) void k_apply(float* __restrict__ out,
                                               const float* __restrict__ s2, const float* __restrict__ q2,
                                               const float* __restrict__ gamma2, const float* __restrict__ beta2) {
    __shared__ float sA[64], sC[64];
    int t = threadIdx.x;
    if (t < 64) {
        float s = 0.f, q = 0.f;
#pragma unroll
        for (int r = 0; r < 8; ++r) { s += s2[r * 64 + t]; q += q2[r * 64 + t]; }
        float mu = s * (1.0f / N_NODES);
        float var = fmaxf(q * (1.0f / N_NODES) - mu * mu, 0.f);
        float av = gamma2[t] * rsqrtf(var + BN_EPS);
        sA[t] = av; sC[t] = beta2[t] - mu * av;
    }
    __syncthreads();
    int idx = blockIdx.x * 1024 + t * 4;
    int ch = (t & 15) * 4;
    float4 v = *(float4*)(out + idx);
    v.x = fmaf(sA[ch+0], v.x, sC[ch+0]);
    v.y = fmaf(sA[ch+1], v.y, sC[ch+1]);
    v.z = fmaf(sA[ch+2], v.z, sC[ch+2]);
    v.w = fmaf(sA[ch+3], v.w, sC[ch+3]);
    *(float4*)(out + idx) = v;
}

extern "C" void kernel_launch(void* const* d_in, const int* in_sizes, int n_in,
                              void* d_out, int out_size, void* d_ws, size_t ws_size,
                              hipStream_t stream) {
    const float* x        = (const float*)d_in[0];
    const int*   ei       = (const int*)d_in[1];
    const float* Wl       = (const float*)d_in[2];
    const float* bl       = (const float*)d_in[3];
    const float* Wr       = (const float*)d_in[4];
    const float* br       = (const float*)d_in[5];
    const float* att      = (const float*)d_in[6];
    const float* bias_gat = (const float*)d_in[7];
    const float* gamma1   = (const float*)d_in[8];
    const float* beta1    = (const float*)d_in[9];
    const float* W1       = (const float*)d_in[10];
    const float* b1       = (const float*)d_in[11];
    const float* W2       = (const float*)d_in[12];
    const float* b2       = (const float*)d_in[13];
    const float* gamma2   = (const float*)d_in[14];
    const float* beta2    = (const float*)d_in[15];
    float* out = (float*)d_out;

    char* ws = (char*)d_ws;
    unsigned short* xlb = (unsigned short*)ws;                         // N*256 bf16
    unsigned short* xrb = xlb + (size_t)N_NODES * HC;                  // N*256 bf16
    float* y1    = (float*)(xrb + (size_t)N_NODES * HC);               // N*64 f32
    int*   perm  = (int*)(y1 + (size_t)N_NODES * HIDDEN);              // N*MAXDEG (not zeroed; k_gat clamps)
    int*   cursor= perm + (size_t)N_NODES * MAXDEG;                    // N    <- zeroed by k_wprep
    float* stats = (float*)(cursor + N_NODES);                         // 2048 <- zeroed by k_wprep
    unsigned short* W1tb  = (unsigned short*)(stats + 2048);           // 64*256
    unsigned short* W2tb  = W1tb + 16384;                              // 256*64
    unsigned short* Wlrtb = W2tb + 16384;                              // 2 * 64*256

    // stats layout: [0:512) gsum1, [512:1024) gsq1, [1024:1536) gsum2, [1536:2048) gsq2 (8 replicas x 64)
    k_wprep<<<256, 256, 0, stream>>>(W1, W2, Wl, Wr, W1tb, W2tb, Wlrtb, cursor);
    k_prep <<<NB_LIN + NB_FILL, 256, 0, stream>>>(x, Wlrtb, bl, br, xlb, xrb, ei, cursor, perm);
    k_gat  <<<N_NODES / 8, 256, 0, stream>>>(xlb, xrb, att, perm, cursor, x, bias_gat, y1,
                                             stats + 0, stats + 512);
    k_ffn  <<<(N_NODES + 63) / 64, 256, 0, stream>>>(y1, stats + 0, stats + 512, gamma1, beta1,
                                                     W1tb, b1, W2tb, b2, out,
                                                     stats + 1024, stats + 1536);
    k_apply<<<N_NODES * HIDDEN / 1024, 256, 0, stream>>>(out, stats + 1024, stats + 1536, gamma2, beta2);
}

// Round 13
// 90.997 us; speedup vs baseline: 1.0566x; 1.0566x over previous
//
#include <hip/hip_runtime.h>
#include <hip/hip_bf16.h>
#include <math.h>

#define N_NODES 20000
#define N_EDGES 320000
#define HIDDEN 64
#define HEADS 4
#define HC 256              // HEADS*HIDDEN
#define D_INNER 256
#define NEG_SLOPE 0.2f
#define BN_EPS 1e-5f
#define MAXDEG 64           // Poisson(16) max load over 20000 bins ~40; P(>64) ~ 1e-19
#define NZERO (N_NODES + 2048)   // cursor + 8-replica stat banks
#define NB_LIN 626          // 2 * ceil(20000/64)
#define NB_FILL 1250        // 320000/256

typedef __attribute__((ext_vector_type(8))) short short8;
typedef __attribute__((ext_vector_type(4))) float f32x4;

__device__ __forceinline__ float bf2f(unsigned short u) {
    unsigned x = ((unsigned)u) << 16;
    return __uint_as_float(x);
}
__device__ __forceinline__ unsigned short f2bf(float f) {
    __hip_bfloat16 b = __float2bfloat16(f);
    return *reinterpret_cast<unsigned short*>(&b);
}
__device__ __forceinline__ void cvt8(uint4 u, float* f) {
    f[0] = __uint_as_float(u.x << 16); f[1] = __uint_as_float(u.x & 0xFFFF0000u);
    f[2] = __uint_as_float(u.y << 16); f[3] = __uint_as_float(u.y & 0xFFFF0000u);
    f[4] = __uint_as_float(u.z << 16); f[5] = __uint_as_float(u.z & 0xFFFF0000u);
    f[6] = __uint_as_float(u.w << 16); f[7] = __uint_as_float(u.w & 0xFFFF0000u);
}

// ---- weight prep: bf16 transposed W1,W2,Wl,Wr + zero cursor/stats + zero perm ----
__global__ __launch_bounds__(256) void k_wprep(const float* __restrict__ W1, const float* __restrict__ W2,
                                               const float* __restrict__ Wl, const float* __restrict__ Wr,
                                               unsigned short* __restrict__ W1tb, unsigned short* __restrict__ W2tb,
                                               unsigned short* __restrict__ Wlrtb,
                                               int* __restrict__ zbuf, int* __restrict__ perm) {
    int idx = blockIdx.x * 256 + threadIdx.x;      // 256*256 = 65536 threads
    if (idx < NZERO) zbuf[idx] = 0;
    int4 z4 = {0, 0, 0, 0};
    int4* p4 = (int4*)perm;
#pragma unroll
    for (int i = 0; i < 5; ++i) {                  // 5*65536 = 327680 >= N*MAXDEG/4
        int k = idx + i * 65536;
        if (k < N_NODES * MAXDEG / 4) p4[k] = z4;
    }
    if (idx < 16384) {
        int k = idx >> 8, n = idx & 255;
        W1tb[n * 64 + k] = f2bf(W1[idx]);
    } else if (idx < 32768) {
        int j = idx - 16384;
        int k = j >> 6, n = j & 63;
        W2tb[n * 256 + k] = f2bf(W2[j]);
    } else if (idx < 49152) {
        int j = idx - 32768;
        int k = j >> 8, n = j & 255;
        Wlrtb[n * 64 + k] = f2bf(Wl[j]);
    } else {
        int j = idx - 49152;
        int k = j >> 8, n = j & 255;
        Wlrtb[16384 + n * 64 + k] = f2bf(Wr[j]);
    }
}

// ---- fused: blocks [0,NB_LIN) do MFMA x@Wl/Wr -> xlb/xrb ; rest do edge bucket fill ----
__global__ __launch_bounds__(256) void k_prep(const float* __restrict__ x,
                                              const unsigned short* __restrict__ Wlrtb,
                                              const float* __restrict__ bl, const float* __restrict__ br,
                                              unsigned short* __restrict__ xlb, unsigned short* __restrict__ xrb,
                                              const int* __restrict__ ei,
                                              int* __restrict__ cursor, int* __restrict__ perm) {
    __shared__ unsigned short sW[16384];   // 32KB [256n][64k] swizzled (linm role only)
    int t = threadIdx.x;
    if (blockIdx.x >= NB_LIN) {
        int e = (blockIdx.x - NB_LIN) * 256 + t;
        int ed = ei[N_EDGES + e];
        int slot = atomicAdd(&cursor[ed], 1);
        perm[ed * MAXDEG + slot] = ei[e];
        return;
    }
    int w = t >> 6, lane = t & 63;
    int l15 = lane & 15, lg = lane >> 4;
    int side = blockIdx.x & 1;
    int row0 = (blockIdx.x >> 1) * 64;
    const float* bias = side ? br : bl;
    unsigned short* dst = side ? xrb : xlb;
    {
        const short8* src = (const short8*)(Wlrtb + side * 16384);
#pragma unroll
        for (int it = 0; it < 8; ++it) {
            int i = it * 256 + t;
            int n = i >> 3, c = i & 7;
            *(short8*)((char*)sW + n * 128 + ((c * 16) ^ ((n & 7) << 4))) = src[i];
        }
    }
    short8 af[4][2];
#pragma unroll
    for (int mt = 0; mt < 4; ++mt) {
        int gm = row0 + mt * 16 + l15;
        bool valid = gm < N_NODES;
#pragma unroll
        for (int kk = 0; kk < 2; ++kk) {
            int k0 = kk * 32 + lg * 8;
            float4 v0 = {0.f,0.f,0.f,0.f}, v1 = {0.f,0.f,0.f,0.f};
            if (valid) {
                v0 = *(const float4*)(x + (size_t)gm * 64 + k0);
                v1 = *(const float4*)(x + (size_t)gm * 64 + k0 + 4);
            }
            short8 f;
            f[0] = (short)f2bf(v0.x); f[1] = (short)f2bf(v0.y);
            f[2] = (short)f2bf(v0.z); f[3] = (short)f2bf(v0.w);
            f[4] = (short)f2bf(v1.x); f[5] = (short)f2bf(v1.y);
            f[6] = (short)f2bf(v1.z); f[7] = (short)f2bf(v1.w);
            af[mt][kk] = f;
        }
    }
    float bv[4];
#pragma unroll
    for (int nt = 0; nt < 4; ++nt) bv[nt] = bias[w * 64 + nt * 16 + l15];
    __syncthreads();
    f32x4 zero4 = {0.f, 0.f, 0.f, 0.f};
    f32x4 acc[4][4];
#pragma unroll
    for (int mt = 0; mt < 4; ++mt)
#pragma unroll
        for (int nt = 0; nt < 4; ++nt) acc[mt][nt] = zero4;
#pragma unroll
    for (int kk = 0; kk < 2; ++kk) {
        int kb = kk * 64 + lg * 16;
        short8 bf[4];
#pragma unroll
        for (int nt = 0; nt < 4; ++nt) {
            int n = w * 64 + nt * 16 + l15;
            bf[nt] = *(const short8*)((const char*)sW + n * 128 + (kb ^ ((n & 7) << 4)));
        }
#pragma unroll
        for (int mt = 0; mt < 4; ++mt)
#pragma unroll
            for (int nt = 0; nt < 4; ++nt)
                acc[mt][nt] = __builtin_amdgcn_mfma_f32_16x16x32_bf16(af[mt][kk], bf[nt], acc[mt][nt], 0, 0, 0);
    }
#pragma unroll
    for (int mt = 0; mt < 4; ++mt)
#pragma unroll
        for (int nt = 0; nt < 4; ++nt) {
            int n = w * 64 + nt * 16 + l15;
#pragma unroll
            for (int r = 0; r < 4; ++r) {
                int gm = row0 + mt * 16 + lg * 4 + r;
                if (gm < N_NODES)
                    dst[(size_t)gm * 256 + n] = f2bf(acc[mt][nt][r] + bv[nt]);
            }
        }
}

// ---- fused GATv2 + residual + BN1 stats: 1 node/wave, halves = consecutive edges ----
__global__ __launch_bounds__(256) void k_gat(const unsigned short* __restrict__ xlb,
                                             const unsigned short* __restrict__ xrb,
                                             const float* __restrict__ att,
                                             const int* __restrict__ perm,
                                             const int* __restrict__ cnt,
                                             const float* __restrict__ x,
                                             const float* __restrict__ bias,
                                             float* __restrict__ y1,
                                             float* __restrict__ gsum, float* __restrict__ gsq) {
    __shared__ float ps[4][64], pq[4][64];
    int t = threadIdx.x;
    int wv = t >> 6;                        // node slot in block (0..3)
    int node = blockIdx.x * 4 + wv;
    int lane = t & 63;
    int hi = lane >> 5;                     // which edge of the pair this half handles
    int l = lane & 31;                      // lane owns flat features [l*8, l*8+8)
    const uint4* xl4 = (const uint4*)xlb;
    uint4 xru = ((const uint4*)xrb)[(size_t)node * 32 + l];
    float xr[8]; cvt8(xru, xr);
    float at[8];
    *(float4*)(at)     = *(const float4*)(att + l * 8);
    *(float4*)(at + 4) = *(const float4*)(att + l * 8 + 4);
    int deg = cnt[node];
    const int* ep = perm + (size_t)node * MAXDEG;
    float d = 0.f;
    float acc[8] = {0.f,0.f,0.f,0.f,0.f,0.f,0.f,0.f};
    // perm rows fully zeroed beyond deg -> unconditional loads safe (gather node 0)
    uint4 b0 = xl4[(size_t)ep[hi] * 32 + l];          // edges 0,1
    uint4 b1 = xl4[(size_t)ep[2 + hi] * 32 + l];      // edges 2,3
    for (int j = 0; j < deg; j += 2) {
        uint4 nx = xl4[(size_t)ep[j + 4 + hi] * 32 + l];   // j+5 <= deg+4 < MAXDEG
        float xl[8]; cvt8(b0, xl);
        float sv = 0.f, sa = 0.f;
#pragma unroll
        for (int i = 0; i < 8; ++i) {
            float v = xl[i] + xr[i];
            sv = fmaf(at[i], v, sv);
            sa = fmaf(at[i], fabsf(v), sa);
        }
        // a . lrelu(v) = 0.6 (a.v) + 0.4 (a.|v|)  for slope 0.2
        float s = 0.6f * sv + 0.4f * sa;
        s += __shfl_xor(s, 1);
        s += __shfl_xor(s, 2);
        s += __shfl_xor(s, 4);              // head score in all 8 lanes of head group
        float w = (j + hi < deg) ? __expf(s) : 0.f;   // scores bounded ~|7|: no-max safe
        d += w;
#pragma unroll
        for (int i = 0; i < 8; ++i) acc[i] = fmaf(w, xl[i], acc[i]);
        b0 = b1; b1 = nx;
    }
    // merge the two halves (edge-parity split), then normalize + head-mean
    d += __shfl_xor(d, 32);
    float inv = 1.f / fmaxf(d, 1e-16f);
#pragma unroll
    for (int i = 0; i < 8; ++i) {
        float v2 = acc[i] + __shfl_xor(acc[i], 32);
        v2 *= inv;
        v2 += __shfl_xor(v2, 8);            // combine 4 heads (same channel slice)
        v2 += __shfl_xor(v2, 16);
        acc[i] = v2;
    }
    if (lane < 8) {
        float4 xv0 = *(const float4*)(x + (size_t)node * 64 + lane * 8);
        float4 xv1 = *(const float4*)(x + (size_t)node * 64 + lane * 8 + 4);
        float4 bv0 = *(const float4*)(bias + lane * 8);
        float4 bv1 = *(const float4*)(bias + lane * 8 + 4);
        float4 y0, y1v;
        y0.x = xv0.x + 0.25f * acc[0] + bv0.x;
        y0.y = xv0.y + 0.25f * acc[1] + bv0.y;
        y0.z = xv0.z + 0.25f * acc[2] + bv0.z;
        y0.w = xv0.w + 0.25f * acc[3] + bv0.w;
        y1v.x = xv1.x + 0.25f * acc[4] + bv1.x;
        y1v.y = xv1.y + 0.25f * acc[5] + bv1.y;
        y1v.z = xv1.z + 0.25f * acc[6] + bv1.z;
        y1v.w = xv1.w + 0.25f * acc[7] + bv1.w;
        *(float4*)(y1 + (size_t)node * 64 + lane * 8) = y0;
        *(float4*)(y1 + (size_t)node * 64 + lane * 8 + 4) = y1v;
        int c = lane * 8;
        ps[wv][c+0] = y0.x; ps[wv][c+1] = y0.y; ps[wv][c+2] = y0.z; ps[wv][c+3] = y0.w;
        ps[wv][c+4] = y1v.x; ps[wv][c+5] = y1v.y; ps[wv][c+6] = y1v.z; ps[wv][c+7] = y1v.w;
        pq[wv][c+0] = y0.x*y0.x; pq[wv][c+1] = y0.y*y0.y; pq[wv][c+2] = y0.z*y0.z; pq[wv][c+3] = y0.w*y0.w;
        pq[wv][c+4] = y1v.x*y1v.x; pq[wv][c+5] = y1v.y*y1v.y; pq[wv][c+6] = y1v.z*y1v.z; pq[wv][c+7] = y1v.w*y1v.w;
    }
    __syncthreads();
    if (t < 64) {
        float s = ps[0][t] + ps[1][t] + ps[2][t] + ps[3][t];
        float q = pq[0][t] + pq[1][t] + pq[2][t] + pq[3][t];
        int rb = blockIdx.x & 7;
        atomicAdd(&gsum[rb * 64 + t], s);
        atomicAdd(&gsq [rb * 64 + t], q);
    }
}

// ---- FFN via MFMA + inline BN1 coef + BN2 partial stats (round-9 verified version) ----
__global__ __launch_bounds__(256) void k_ffn(const float* __restrict__ y1,
                                             const float* __restrict__ s1, const float* __restrict__ q1,
                                             const float* __restrict__ gamma1, const float* __restrict__ beta1,
                                             const unsigned short* __restrict__ W1tb, const float* __restrict__ b1,
                                             const unsigned short* __restrict__ W2tb, const float* __restrict__ b2,
                                             float* __restrict__ out,
                                             float* __restrict__ gsum2, float* __restrict__ gsq2) {
    __shared__ unsigned short sW[16384];   // 32KB: W1t during GEMM1, W2t during GEMM2
    __shared__ unsigned short sH[16384];   // 32KB: relu hidden, bf16 [64][256]
    __shared__ __align__(16) float sA1[64], sC1[64];
    int t = threadIdx.x;
    int w = t >> 6, lane = t & 63;
    int l15 = lane & 15, lg = lane >> 4;
    int blk = blockIdx.x;

    {
        const short8* src = (const short8*)W1tb;
#pragma unroll
        for (int it = 0; it < 8; ++it) {
            int i = it * 256 + t;
            int n = i >> 3, c = i & 7;
            *(short8*)((char*)sW + n * 128 + ((c * 16) ^ ((n & 7) << 4))) = src[i];
        }
    }
    if (t < 64) {
        float s = 0.f, q = 0.f;
#pragma unroll
        for (int r = 0; r < 8; ++r) { s += s1[r * 64 + t]; q += q1[r * 64 + t]; }
        float mu = s * (1.0f / N_NODES);
        float var = fmaxf(q * (1.0f / N_NODES) - mu * mu, 0.f);
        float av = gamma1[t] * rsqrtf(var + BN_EPS);
        sA1[t] = av; sC1[t] = beta1[t] - mu * av;
    }
    __syncthreads();

    float4 a1k[2][2], c1k[2][2];
#pragma unroll
    for (int kk = 0; kk < 2; ++kk) {
        int k0 = kk * 32 + lg * 8;
        a1k[kk][0] = *(const float4*)(sA1 + k0); a1k[kk][1] = *(const float4*)(sA1 + k0 + 4);
        c1k[kk][0] = *(const float4*)(sC1 + k0); c1k[kk][1] = *(const float4*)(sC1 + k0 + 4);
    }
    short8 af[4][2];
#pragma unroll
    for (int mt = 0; mt < 4; ++mt) {
        int gm = blk * 64 + mt * 16 + l15;
        bool valid = gm < N_NODES;
#pragma unroll
        for (int kk = 0; kk < 2; ++kk) {
            int k0 = kk * 32 + lg * 8;
            float4 v0 = {0.f,0.f,0.f,0.f}, v1 = {0.f,0.f,0.f,0.f};
            if (valid) {
                v0 = *(const float4*)(y1 + (size_t)gm * 64 + k0);
                v1 = *(const float4*)(y1 + (size_t)gm * 64 + k0 + 4);
            }
            short8 f;
            f[0] = (short)f2bf(fmaf(a1k[kk][0].x, v0.x, c1k[kk][0].x));
            f[1] = (short)f2bf(fmaf(a1k[kk][0].y, v0.y, c1k[kk][0].y));
            f[2] = (short)f2bf(fmaf(a1k[kk][0].z, v0.z, c1k[kk][0].z));
            f[3] = (short)f2bf(fmaf(a1k[kk][0].w, v0.w, c1k[kk][0].w));
            f[4] = (short)f2bf(fmaf(a1k[kk][1].x, v1.x, c1k[kk][1].x));
            f[5] = (short)f2bf(fmaf(a1k[kk][1].y, v1.y, c1k[kk][1].y));
            f[6] = (short)f2bf(fmaf(a1k[kk][1].z, v1.z, c1k[kk][1].z));
            f[7] = (short)f2bf(fmaf(a1k[kk][1].w, v1.w, c1k[kk][1].w));
            af[mt][kk] = f;
        }
    }
    float b1v[4];
#pragma unroll
    for (int nt = 0; nt < 4; ++nt) b1v[nt] = b1[w * 64 + nt * 16 + l15];

    f32x4 zero4 = {0.f, 0.f, 0.f, 0.f};
    f32x4 acc[4][4];
#pragma unroll
    for (int mt = 0; mt < 4; ++mt)
#pragma unroll
        for (int nt = 0; nt < 4; ++nt) acc[mt][nt] = zero4;
#pragma unroll
    for (int kk = 0; kk < 2; ++kk) {
        int kb = kk * 64 + lg * 16;
        short8 bf[4];
#pragma unroll
        for (int nt = 0; nt < 4; ++nt) {
            int n = w * 64 + nt * 16 + l15;
            bf[nt] = *(const short8*)((const char*)sW + n * 128 + (kb ^ ((n & 7) << 4)));
        }
#pragma unroll
        for (int mt = 0; mt < 4; ++mt)
#pragma unroll
            for (int nt = 0; nt < 4; ++nt)
                acc[mt][nt] = __builtin_amdgcn_mfma_f32_16x16x32_bf16(af[mt][kk], bf[nt], acc[mt][nt], 0, 0, 0);
    }
    __syncthreads();

#pragma unroll
    for (int mt = 0; mt < 4; ++mt)
#pragma unroll
        for (int nt = 0; nt < 4; ++nt) {
            int n = w * 64 + nt * 16 + l15;
#pragma unroll
            for (int r = 0; r < 4; ++r) {
                int m = mt * 16 + lg * 4 + r;
                float h = fmaxf(acc[mt][nt][r] + b1v[nt], 0.f);
                *(unsigned short*)((char*)sH + m * 512 + ((n * 2) ^ ((m & 7) << 4))) = f2bf(h);
            }
        }
    {
        const short8* src = (const short8*)W2tb;
#pragma unroll
        for (int it = 0; it < 8; ++it) {
            int i = it * 256 + t;
            int n = i >> 5, c = i & 31;
            *(short8*)((char*)sW + n * 512 + ((c * 16) ^ ((n & 7) << 4))) = src[i];
        }
    }
    __syncthreads();

    f32x4 acc2[4];
#pragma unroll
    for (int nt = 0; nt < 4; ++nt) acc2[nt] = zero4;
#pragma unroll
    for (int kk = 0; kk < 8; ++kk) {
        int kb = kk * 64 + lg * 16;
        int m = w * 16 + l15;
        short8 a2 = *(const short8*)((const char*)sH + m * 512 + (kb ^ ((m & 7) << 4)));
#pragma unroll
        for (int nt = 0; nt < 4; ++nt) {
            int n = nt * 16 + l15;
            short8 b2f = *(const short8*)((const char*)sW + n * 512 + (kb ^ ((n & 7) << 4)));
            acc2[nt] = __builtin_amdgcn_mfma_f32_16x16x32_bf16(a2, b2f, acc2[nt], 0, 0, 0);
        }
    }

    float b2v[4], a1n[4], c1n[4], ssum[4] = {0.f,0.f,0.f,0.f}, ssq[4] = {0.f,0.f,0.f,0.f};
#pragma unroll
    for (int nt = 0; nt < 4; ++nt) {
        int n = nt * 16 + l15;
        b2v[nt] = b2[n]; a1n[nt] = sA1[n]; c1n[nt] = sC1[n];
    }
#pragma unroll
    for (int nt = 0; nt < 4; ++nt) {
        int n = nt * 16 + l15;
#pragma unroll
        for (int r = 0; r < 4; ++r) {
            int gm = blk * 64 + w * 16 + lg * 4 + r;
            if (gm < N_NODES) {
                float v = acc2[nt][r] + b2v[nt] + fmaf(a1n[nt], y1[(size_t)gm * 64 + n], c1n[nt]);
                out[(size_t)gm * 64 + n] = v;
                ssum[nt] += v; ssq[nt] += v * v;
            }
        }
    }
    __syncthreads();
    float* fs = (float*)sW;
#pragma unroll
    for (int nt = 0; nt < 4; ++nt) {
        float ss = ssum[nt], qq = ssq[nt];
        ss += __shfl_xor(ss, 16); ss += __shfl_xor(ss, 32);
        qq += __shfl_xor(qq, 16); qq += __shfl_xor(qq, 32);
        if (lg == 0) {
            int n = nt * 16 + l15;
            fs[w * 64 + n] = ss;
            fs[256 + w * 64 + n] = qq;
        }
    }
    __syncthreads();
    if (t < 64) {
        int r = blk & 7;
        atomicAdd(&gsum2[r * 64 + t], fs[t] + fs[64 + t] + fs[128 + t] + fs[192 + t]);
        atomicAdd(&gsq2 [r * 64 + t], fs[256 + t] + fs[320 + t] + fs[384 + t] + fs[448 + t]);
    }
}

// ---- apply BN2 in-place, float4-vectorized ----
__global__ __launch_bounds__(256) void k_apply(float* __restrict__ out,
                                               const float* __restrict__ s2, const float* __restrict__ q2,
                                               const float* __restrict__ gamma2, const float* __restrict__ beta2) {
    __shared__ float sA[64], sC[64];
    int t = threadIdx.x;
    if (t < 64) {
        float s = 0.f, q = 0.f;
#pragma unroll
        for (int r = 0; r < 8; ++r) { s += s2[r * 64 + t]; q += q2[r * 64 + t]; }
        float mu = s * (1.0f / N_NODES);
        float var = fmaxf(q * (1.0f / N_NODES) - mu * mu, 0.f);
        float av = gamma2[t] * rsqrtf(var + BN_EPS);
        sA[t] = av; sC[t] = beta2[t] - mu * av;
    }
    __syncthreads();
    int idx = blockIdx.x * 1024 + t * 4;
    int ch = (t & 15) * 4;
    float4 v = *(float4*)(out + idx);
    v.x = fmaf(sA[ch+0], v.x, sC[ch+0]);
    v.y = fmaf(sA[ch+1], v.y, sC[ch+1]);
    v.z = fmaf(sA[ch+2], v.z, sC[ch+2]);
    v.w = fmaf(sA[ch+3], v.w, sC[ch+3]);
    *(float4*)(out + idx) = v;
}

extern "C" void kernel_launch(void* const* d_in, const int* in_sizes, int n_in,
                              void* d_out, int out_size, void* d_ws, size_t ws_size,
                              hipStream_t stream) {
    const float* x        = (const float*)d_in[0];
    const int*   ei       = (const int*)d_in[1];
    const float* Wl       = (const float*)d_in[2];
    const float* bl       = (const float*)d_in[3];
    const float* Wr       = (const float*)d_in[4];
    const float* br       = (const float*)d_in[5];
    const float* att      = (const float*)d_in[6];
    const float* bias_gat = (const float*)d_in[7];
    const float* gamma1   = (const float*)d_in[8];
    const float* beta1    = (const float*)d_in[9];
    const float* W1       = (const float*)d_in[10];
    const float* b1       = (const float*)d_in[11];
    const float* W2       = (const float*)d_in[12];
    const float* b2       = (const float*)d_in[13];
    const float* gamma2   = (const float*)d_in[14];
    const float* beta2    = (const float*)d_in[15];
    float* out = (float*)d_out;

    char* ws = (char*)d_ws;
    unsigned short* xlb = (unsigned short*)ws;                         // N*256 bf16
    unsigned short* xrb = xlb + (size_t)N_NODES * HC;                  // N*256 bf16
    float* y1    = (float*)(xrb + (size_t)N_NODES * HC);               // N*64 f32
    int*   perm  = (int*)(y1 + (size_t)N_NODES * HIDDEN);              // N*MAXDEG <- zeroed by k_wprep
    int*   cursor= perm + (size_t)N_NODES * MAXDEG;                    // N    <- zeroed by k_wprep
    float* stats = (float*)(cursor + N_NODES);                         // 2048 <- zeroed by k_wprep
    unsigned short* W1tb  = (unsigned short*)(stats + 2048);           // 64*256
    unsigned short* W2tb  = W1tb + 16384;                              // 256*64
    unsigned short* Wlrtb = W2tb + 16384;                              // 2 * 64*256

    // stats layout: [0:512) gsum1, [512:1024) gsq1, [1024:1536) gsum2, [1536:2048) gsq2 (8 replicas x 64)
    k_wprep<<<256, 256, 0, stream>>>(W1, W2, Wl, Wr, W1tb, W2tb, Wlrtb, cursor, perm);
    k_prep <<<NB_LIN + NB_FILL, 256, 0, stream>>>(x, Wlrtb, bl, br, xlb, xrb, ei, cursor, perm);
    k_gat  <<<N_NODES / 4, 256, 0, stream>>>(xlb, xrb, att, perm, cursor, x, bias_gat, y1,
                                             stats + 0, stats + 512);
    k_ffn  <<<(N_NODES + 63) / 64, 256, 0, stream>>>(y1, stats + 0, stats + 512, gamma1, beta1,
                                                     W1tb, b1, W2tb, b2, out,
                                                     stats + 1024, stats + 1536);
    k_apply<<<N_NODES * HIDDEN / 1024, 256, 0, stream>>>(out, stats + 1024, stats + 1536, gamma2, beta2);
}

// Round 14
// 85.067 us; speedup vs baseline: 1.1303x; 1.0697x over previous
//
#include <hip/hip_runtime.h>
#include <hip/hip_bf16.h>
#include <math.h>

#define N_NODES 20000
#define N_EDGES 320000
#define HIDDEN 64
#define HEADS 4
#define HC 256              // HEADS*HIDDEN
#define D_INNER 256
#define NEG_SLOPE 0.2f
#define BN_EPS 1e-5f
#define MAXDEG 64           // Poisson(16) max load over 20000 bins ~40; P(>64) ~ 1e-19
#define NZERO (N_NODES + 2048)   // cursor + 8-replica stat banks
#define NB_LIN 626          // 2 * ceil(20000/64)
#define NB_FILL 1250        // 320000/256

typedef __attribute__((ext_vector_type(8))) short short8;
typedef __attribute__((ext_vector_type(4))) float f32x4;

__device__ __forceinline__ float bf2f(unsigned short u) {
    unsigned x = ((unsigned)u) << 16;
    return __uint_as_float(x);
}
__device__ __forceinline__ unsigned short f2bf(float f) {
    __hip_bfloat16 b = __float2bfloat16(f);
    return *reinterpret_cast<unsigned short*>(&b);
}
__device__ __forceinline__ void cvt8(uint4 u, float* f) {
    f[0] = __uint_as_float(u.x << 16); f[1] = __uint_as_float(u.x & 0xFFFF0000u);
    f[2] = __uint_as_float(u.y << 16); f[3] = __uint_as_float(u.y & 0xFFFF0000u);
    f[4] = __uint_as_float(u.z << 16); f[5] = __uint_as_float(u.z & 0xFFFF0000u);
    f[6] = __uint_as_float(u.w << 16); f[7] = __uint_as_float(u.w & 0xFFFF0000u);
}

// ---- weight prep: bf16 transposed W1,W2,Wl,Wr + zero cursor/stats + zero perm ----
__global__ __launch_bounds__(256) void k_wprep(const float* __restrict__ W1, const float* __restrict__ W2,
                                               const float* __restrict__ Wl, const float* __restrict__ Wr,
                                               unsigned short* __restrict__ W1tb, unsigned short* __restrict__ W2tb,
                                               unsigned short* __restrict__ Wlrtb,
                                               int* __restrict__ zbuf, int* __restrict__ perm) {
    int idx = blockIdx.x * 256 + threadIdx.x;      // 256*256 = 65536 threads
    if (idx < NZERO) zbuf[idx] = 0;
    int4 z4 = {0, 0, 0, 0};
    int4* p4 = (int4*)perm;
#pragma unroll
    for (int i = 0; i < 5; ++i) {                  // 5*65536 = 327680 >= N*MAXDEG/4
        int k = idx + i * 65536;
        if (k < N_NODES * MAXDEG / 4) p4[k] = z4;
    }
    if (idx < 16384) {
        int k = idx >> 8, n = idx & 255;
        W1tb[n * 64 + k] = f2bf(W1[idx]);
    } else if (idx < 32768) {
        int j = idx - 16384;
        int k = j >> 6, n = j & 63;
        W2tb[n * 256 + k] = f2bf(W2[j]);
    } else if (idx < 49152) {
        int j = idx - 32768;
        int k = j >> 8, n = j & 255;
        Wlrtb[n * 64 + k] = f2bf(Wl[j]);
    } else {
        int j = idx - 49152;
        int k = j >> 8, n = j & 255;
        Wlrtb[16384 + n * 64 + k] = f2bf(Wr[j]);
    }
}

// ---- fused: blocks [0,NB_LIN) do MFMA x@Wl/Wr -> xlb/xrb ; rest do edge bucket fill ----
__global__ __launch_bounds__(256) void k_prep(const float* __restrict__ x,
                                              const unsigned short* __restrict__ Wlrtb,
                                              const float* __restrict__ bl, const float* __restrict__ br,
                                              unsigned short* __restrict__ xlb, unsigned short* __restrict__ xrb,
                                              const int* __restrict__ ei,
                                              int* __restrict__ cursor, int* __restrict__ perm) {
    __shared__ unsigned short sW[16384];   // 32KB [256n][64k] swizzled (linm role only)
    int t = threadIdx.x;
    if (blockIdx.x >= NB_LIN) {
        int e = (blockIdx.x - NB_LIN) * 256 + t;
        int ed = ei[N_EDGES + e];
        int slot = atomicAdd(&cursor[ed], 1);
        perm[ed * MAXDEG + slot] = ei[e];
        return;
    }
    int w = t >> 6, lane = t & 63;
    int l15 = lane & 15, lg = lane >> 4;
    int side = blockIdx.x & 1;
    int row0 = (blockIdx.x >> 1) * 64;
    const float* bias = side ? br : bl;
    unsigned short* dst = side ? xrb : xlb;
    {
        const short8* src = (const short8*)(Wlrtb + side * 16384);
#pragma unroll
        for (int it = 0; it < 8; ++it) {
            int i = it * 256 + t;
            int n = i >> 3, c = i & 7;
            *(short8*)((char*)sW + n * 128 + ((c * 16) ^ ((n & 7) << 4))) = src[i];
        }
    }
    short8 af[4][2];
#pragma unroll
    for (int mt = 0; mt < 4; ++mt) {
        int gm = row0 + mt * 16 + l15;
        bool valid = gm < N_NODES;
#pragma unroll
        for (int kk = 0; kk < 2; ++kk) {
            int k0 = kk * 32 + lg * 8;
            float4 v0 = {0.f,0.f,0.f,0.f}, v1 = {0.f,0.f,0.f,0.f};
            if (valid) {
                v0 = *(const float4*)(x + (size_t)gm * 64 + k0);
                v1 = *(const float4*)(x + (size_t)gm * 64 + k0 + 4);
            }
            short8 f;
            f[0] = (short)f2bf(v0.x); f[1] = (short)f2bf(v0.y);
            f[2] = (short)f2bf(v0.z); f[3] = (short)f2bf(v0.w);
            f[4] = (short)f2bf(v1.x); f[5] = (short)f2bf(v1.y);
            f[6] = (short)f2bf(v1.z); f[7] = (short)f2bf(v1.w);
            af[mt][kk] = f;
        }
    }
    float bv[4];
#pragma unroll
    for (int nt = 0; nt < 4; ++nt) bv[nt] = bias[w * 64 + nt * 16 + l15];
    __syncthreads();
    f32x4 zero4 = {0.f, 0.f, 0.f, 0.f};
    f32x4 acc[4][4];
#pragma unroll
    for (int mt = 0; mt < 4; ++mt)
#pragma unroll
        for (int nt = 0; nt < 4; ++nt) acc[mt][nt] = zero4;
#pragma unroll
    for (int kk = 0; kk < 2; ++kk) {
        int kb = kk * 64 + lg * 16;
        short8 bf[4];
#pragma unroll
        for (int nt = 0; nt < 4; ++nt) {
            int n = w * 64 + nt * 16 + l15;
            bf[nt] = *(const short8*)((const char*)sW + n * 128 + (kb ^ ((n & 7) << 4)));
        }
#pragma unroll
        for (int mt = 0; mt < 4; ++mt)
#pragma unroll
            for (int nt = 0; nt < 4; ++nt)
                acc[mt][nt] = __builtin_amdgcn_mfma_f32_16x16x32_bf16(af[mt][kk], bf[nt], acc[mt][nt], 0, 0, 0);
    }
#pragma unroll
    for (int mt = 0; mt < 4; ++mt)
#pragma unroll
        for (int nt = 0; nt < 4; ++nt) {
            int n = w * 64 + nt * 16 + l15;
#pragma unroll
            for (int r = 0; r < 4; ++r) {
                int gm = row0 + mt * 16 + lg * 4 + r;
                if (gm < N_NODES)
                    dst[(size_t)gm * 256 + n] = f2bf(acc[mt][nt][r] + bv[nt]);
            }
        }
}

// ---- fused GATv2 + residual + BN1 stats: 2 nodes/wave, 2 edges/iter ILP, no-max softmax ----
__global__ __launch_bounds__(256) void k_gat(const unsigned short* __restrict__ xlb,
                                             const unsigned short* __restrict__ xrb,
                                             const float* __restrict__ att,
                                             const int* __restrict__ perm,
                                             const int* __restrict__ cnt,
                                             const float* __restrict__ x,
                                             const float* __restrict__ bias,
                                             float* __restrict__ y1,
                                             float* __restrict__ gsum, float* __restrict__ gsq) {
    __shared__ float ps[8][64], pq[8][64];
    int t = threadIdx.x;
    int hw = t >> 5, l = t & 31;            // half-wave id, lane-in-half
    int node = blockIdx.x * 8 + hw;
    const uint4* xl4 = (const uint4*)xlb;
    // lane l owns flat features [l*8, l*8+8) -> head l>>3
    uint4 xru = ((const uint4*)xrb)[(size_t)node * 32 + l];
    float xr[8]; cvt8(xru, xr);
    float at[8];
    *(float4*)(at)     = *(const float4*)(att + l * 8);
    *(float4*)(at + 4) = *(const float4*)(att + l * 8 + 4);
    int deg = cnt[node];
    int mdeg = max(deg, __shfl_xor(deg, 32));
    const int* ep = perm + (size_t)node * MAXDEG;
    float d = 0.f;
    float acc[8] = {0.f,0.f,0.f,0.f,0.f,0.f,0.f,0.f};
    // perm rows fully zeroed beyond deg -> unconditional loads safe (gather node 0)
    uint4 b0 = xl4[(size_t)ep[0] * 32 + l];
    uint4 b1 = xl4[(size_t)ep[1] * 32 + l];
    uint4 b2 = xl4[(size_t)ep[2] * 32 + l];
    uint4 b3 = xl4[(size_t)ep[3] * 32 + l];
    for (int j = 0; j < mdeg; j += 2) {
        uint4 n0 = xl4[(size_t)ep[j + 4] * 32 + l];   // j+5 <= mdeg+3 < MAXDEG
        uint4 n1 = xl4[(size_t)ep[j + 5] * 32 + l];
        float xl0[8], xl1[8];
        cvt8(b0, xl0); cvt8(b1, xl1);
        float sv0 = 0.f, sa0 = 0.f, sv1 = 0.f, sa1 = 0.f;
#pragma unroll
        for (int i = 0; i < 8; ++i) {
            float v0 = xl0[i] + xr[i];
            float v1 = xl1[i] + xr[i];
            sv0 = fmaf(at[i], v0, sv0);
            sa0 = fmaf(at[i], fabsf(v0), sa0);
            sv1 = fmaf(at[i], v1, sv1);
            sa1 = fmaf(at[i], fabsf(v1), sa1);
        }
        // a . lrelu(v) = 0.6 (a.v) + 0.4 (a.|v|)  for slope 0.2
        float s0 = 0.6f * sv0 + 0.4f * sa0;
        float s1 = 0.6f * sv1 + 0.4f * sa1;
        s0 += __shfl_xor(s0, 1); s1 += __shfl_xor(s1, 1);
        s0 += __shfl_xor(s0, 2); s1 += __shfl_xor(s1, 2);
        s0 += __shfl_xor(s0, 4); s1 += __shfl_xor(s1, 4);
        float w0 = (j < deg)     ? __expf(s0) : 0.f;  // scores bounded ~|7|: no-max safe
        float w1 = (j + 1 < deg) ? __expf(s1) : 0.f;
        d += w0 + w1;
#pragma unroll
        for (int i = 0; i < 8; ++i)
            acc[i] = fmaf(w0, xl0[i], fmaf(w1, xl1[i], acc[i]));
        b0 = b2; b1 = b3; b2 = n0; b3 = n1;
    }
    float inv = 1.f / fmaxf(d, 1e-16f);
#pragma unroll
    for (int i = 0; i < 8; ++i) {
        float v2 = acc[i] * inv;
        v2 += __shfl_xor(v2, 8);             // combine 4 heads (same channel slice)
        v2 += __shfl_xor(v2, 16);
        acc[i] = v2;
    }
    if (l < 8) {
        float4 xv0 = *(const float4*)(x + (size_t)node * 64 + l * 8);
        float4 xv1 = *(const float4*)(x + (size_t)node * 64 + l * 8 + 4);
        float4 bv0 = *(const float4*)(bias + l * 8);
        float4 bv1 = *(const float4*)(bias + l * 8 + 4);
        float4 y0, y1v;
        y0.x = xv0.x + 0.25f * acc[0] + bv0.x;
        y0.y = xv0.y + 0.25f * acc[1] + bv0.y;
        y0.z = xv0.z + 0.25f * acc[2] + bv0.z;
        y0.w = xv0.w + 0.25f * acc[3] + bv0.w;
        y1v.x = xv1.x + 0.25f * acc[4] + bv1.x;
        y1v.y = xv1.y + 0.25f * acc[5] + bv1.y;
        y1v.z = xv1.z + 0.25f * acc[6] + bv1.z;
        y1v.w = xv1.w + 0.25f * acc[7] + bv1.w;
        *(float4*)(y1 + (size_t)node * 64 + l * 8) = y0;
        *(float4*)(y1 + (size_t)node * 64 + l * 8 + 4) = y1v;
        int c = l * 8;
        ps[hw][c+0] = y0.x; ps[hw][c+1] = y0.y; ps[hw][c+2] = y0.z; ps[hw][c+3] = y0.w;
        ps[hw][c+4] = y1v.x; ps[hw][c+5] = y1v.y; ps[hw][c+6] = y1v.z; ps[hw][c+7] = y1v.w;
        pq[hw][c+0] = y0.x*y0.x; pq[hw][c+1] = y0.y*y0.y; pq[hw][c+2] = y0.z*y0.z; pq[hw][c+3] = y0.w*y0.w;
        pq[hw][c+4] = y1v.x*y1v.x; pq[hw][c+5] = y1v.y*y1v.y; pq[hw][c+6] = y1v.z*y1v.z; pq[hw][c+7] = y1v.w*y1v.w;
    }
    __syncthreads();
    if (t < 64) {
        float s = 0.f, q = 0.f;
#pragma unroll
        for (int r = 0; r < 8; ++r) { s += ps[r][t]; q += pq[r][t]; }
        int rb = blockIdx.x & 7;
        atomicAdd(&gsum[rb * 64 + t], s);
        atomicAdd(&gsq [rb * 64 + t], q);
    }
}

// ---- FFN via MFMA + inline BN1 coef + BN2 partial stats ----
__global__ __launch_bounds__(256) void k_ffn(const float* __restrict__ y1,
                                             const float* __restrict__ s1, const float* __restrict__ q1,
                                             const float* __restrict__ gamma1, const float* __restrict__ beta1,
                                             const unsigned short* __restrict__ W1tb, const float* __restrict__ b1,
                                             const unsigned short* __restrict__ W2tb, const float* __restrict__ b2,
                                             float* __restrict__ out,
                                             float* __restrict__ gsum2, float* __restrict__ gsq2) {
    __shared__ unsigned short sW[16384];   // 32KB: W1t during GEMM1, W2t during GEMM2
    __shared__ unsigned short sH[16384];   // 32KB: relu hidden, bf16 [64][256]
    __shared__ __align__(16) float sA1[64], sC1[64];
    int t = threadIdx.x;
    int w = t >> 6, lane = t & 63;
    int l15 = lane & 15, lg = lane >> 4;
    int blk = blockIdx.x;

    {
        const short8* src = (const short8*)W1tb;
#pragma unroll
        for (int it = 0; it < 8; ++it) {
            int i = it * 256 + t;
            int n = i >> 3, c = i & 7;
            *(short8*)((char*)sW + n * 128 + ((c * 16) ^ ((n & 7) << 4))) = src[i];
        }
    }
    if (t < 64) {
        float s = 0.f, q = 0.f;
#pragma unroll
        for (int r = 0; r < 8; ++r) { s += s1[r * 64 + t]; q += q1[r * 64 + t]; }
        float mu = s * (1.0f / N_NODES);
        float var = fmaxf(q * (1.0f / N_NODES) - mu * mu, 0.f);
        float av = gamma1[t] * rsqrtf(var + BN_EPS);
        sA1[t] = av; sC1[t] = beta1[t] - mu * av;
    }
    __syncthreads();

    float4 a1k[2][2], c1k[2][2];
#pragma unroll
    for (int kk = 0; kk < 2; ++kk) {
        int k0 = kk * 32 + lg * 8;
        a1k[kk][0] = *(const float4*)(sA1 + k0); a1k[kk][1] = *(const float4*)(sA1 + k0 + 4);
        c1k[kk][0] = *(const float4*)(sC1 + k0); c1k[kk][1] = *(const float4*)(sC1 + k0 + 4);
    }
    short8 af[4][2];
#pragma unroll
    for (int mt = 0; mt < 4; ++mt) {
        int gm = blk * 64 + mt * 16 + l15;
        bool valid = gm < N_NODES;
#pragma unroll
        for (int kk = 0; kk < 2; ++kk) {
            int k0 = kk * 32 + lg * 8;
            float4 v0 = {0.f,0.f,0.f,0.f}, v1 = {0.f,0.f,0.f,0.f};
            if (valid) {
                v0 = *(const float4*)(y1 + (size_t)gm * 64 + k0);
                v1 = *(const float4*)(y1 + (size_t)gm * 64 + k0 + 4);
            }
            short8 f;
            f[0] = (short)f2bf(fmaf(a1k[kk][0].x, v0.x, c1k[kk][0].x));
            f[1] = (short)f2bf(fmaf(a1k[kk][0].y, v0.y, c1k[kk][0].y));
            f[2] = (short)f2bf(fmaf(a1k[kk][0].z, v0.z, c1k[kk][0].z));
            f[3] = (short)f2bf(fmaf(a1k[kk][0].w, v0.w, c1k[kk][0].w));
            f[4] = (short)f2bf(fmaf(a1k[kk][1].x, v1.x, c1k[kk][1].x));
            f[5] = (short)f2bf(fmaf(a1k[kk][1].y, v1.y, c1k[kk][1].y));
            f[6] = (short)f2bf(fmaf(a1k[kk][1].z, v1.z, c1k[kk][1].z));
            f[7] = (short)f2bf(fmaf(a1k[kk][1].w, v1.w, c1k[kk][1].w));
            af[mt][kk] = f;
        }
    }
    float b1v[4];
#pragma unroll
    for (int nt = 0; nt < 4; ++nt) b1v[nt] = b1[w * 64 + nt * 16 + l15];

    f32x4 zero4 = {0.f, 0.f, 0.f, 0.f};
    f32x4 acc[4][4];
#pragma unroll
    for (int mt = 0; mt < 4; ++mt)
#pragma unroll
        for (int nt = 0; nt < 4; ++nt) acc[mt][nt] = zero4;
#pragma unroll
    for (int kk = 0; kk < 2; ++kk) {
        int kb = kk * 64 + lg * 16;
        short8 bf[4];
#pragma unroll
        for (int nt = 0; nt < 4; ++nt) {
            int n = w * 64 + nt * 16 + l15;
            bf[nt] = *(const short8*)((const char*)sW + n * 128 + (kb ^ ((n & 7) << 4)));
        }
#pragma unroll
        for (int mt = 0; mt < 4; ++mt)
#pragma unroll
            for (int nt = 0; nt < 4; ++nt)
                acc[mt][nt] = __builtin_amdgcn_mfma_f32_16x16x32_bf16(af[mt][kk], bf[nt], acc[mt][nt], 0, 0, 0);
    }
    __syncthreads();

#pragma unroll
    for (int mt = 0; mt < 4; ++mt)
#pragma unroll
        for (int nt = 0; nt < 4; ++nt) {
            int n = w * 64 + nt * 16 + l15;
#pragma unroll
            for (int r = 0; r < 4; ++r) {
                int m = mt * 16 + lg * 4 + r;
                float h = fmaxf(acc[mt][nt][r] + b1v[nt], 0.f);
                *(unsigned short*)((char*)sH + m * 512 + ((n * 2) ^ ((m & 7) << 4))) = f2bf(h);
            }
        }
    {
        const short8* src = (const short8*)W2tb;
#pragma unroll
        for (int it = 0; it < 8; ++it) {
            int i = it * 256 + t;
            int n = i >> 5, c = i & 31;
            *(short8*)((char*)sW + n * 512 + ((c * 16) ^ ((n & 7) << 4))) = src[i];
        }
    }
    __syncthreads();

    f32x4 acc2[4];
#pragma unroll
    for (int nt = 0; nt < 4; ++nt) acc2[nt] = zero4;
#pragma unroll
    for (int kk = 0; kk < 8; ++kk) {
        int kb = kk * 64 + lg * 16;
        int m = w * 16 + l15;
        short8 a2 = *(const short8*)((const char*)sH + m * 512 + (kb ^ ((m & 7) << 4)));
#pragma unroll
        for (int nt = 0; nt < 4; ++nt) {
            int n = nt * 16 + l15;
            short8 b2f = *(const short8*)((const char*)sW + n * 512 + (kb ^ ((n & 7) << 4)));
            acc2[nt] = __builtin_amdgcn_mfma_f32_16x16x32_bf16(a2, b2f, acc2[nt], 0, 0, 0);
        }
    }

    float b2v[4], a1n[4], c1n[4], ssum[4] = {0.f,0.f,0.f,0.f}, ssq[4] = {0.f,0.f,0.f,0.f};
#pragma unroll
    for (int nt = 0; nt < 4; ++nt) {
        int n = nt * 16 + l15;
        b2v[nt] = b2[n]; a1n[nt] = sA1[n]; c1n[nt] = sC1[n];
    }
#pragma unroll
    for (int nt = 0; nt < 4; ++nt) {
        int n = nt * 16 + l15;
#pragma unroll
        for (int r = 0; r < 4; ++r) {
            int gm = blk * 64 + w * 16 + lg * 4 + r;
            if (gm < N_NODES) {
                float v = acc2[nt][r] + b2v[nt] + fmaf(a1n[nt], y1[(size_t)gm * 64 + n], c1n[nt]);
                out[(size_t)gm * 64 + n] = v;
                ssum[nt] += v; ssq[nt] += v * v;
            }
        }
    }
    __syncthreads();
    float* fs = (float*)sW;
#pragma unroll
    for (int nt = 0; nt < 4; ++nt) {
        float ss = ssum[nt], qq = ssq[nt];
        ss += __shfl_xor(ss, 16); ss += __shfl_xor(ss, 32);
        qq += __shfl_xor(qq, 16); qq += __shfl_xor(qq, 32);
        if (lg == 0) {
            int n = nt * 16 + l15;
            fs[w * 64 + n] = ss;
            fs[256 + w * 64 + n] = qq;
        }
    }
    __syncthreads();
    if (t < 64) {
        int r = blk & 7;
        atomicAdd(&gsum2[r * 64 + t], fs[t] + fs[64 + t] + fs[128 + t] + fs[192 + t]);
        atomicAdd(&gsq2 [r * 64 + t], fs[256 + t] + fs[320 + t] + fs[384 + t] + fs[448 + t]);
    }
}

// ---- apply BN2 in-place, float4-vectorized ----
__global__ __launch_bounds__(256) void k_apply(float* __restrict__ out,
                                               const float* __restrict__ s2, const float* __restrict__ q2,
                                               const float* __restrict__ gamma2, const float* __restrict__ beta2) {
    __shared__ float sA[64], sC[64];
    int t = threadIdx.x;
    if (t < 64) {
        float s = 0.f, q = 0.f;
#pragma unroll
        for (int r = 0; r < 8; ++r) { s += s2[r * 64 + t]; q += q2[r * 64 + t]; }
        float mu = s * (1.0f / N_NODES);
        float var = fmaxf(q * (1.0f / N_NODES) - mu * mu, 0.f);
        float av = gamma2[t] * rsqrtf(var + BN_EPS);
        sA[t] = av; sC[t] = beta2[t] - mu * av;
    }
    __syncthreads();
    int idx = blockIdx.x * 1024 + t * 4;
    int ch = (t & 15) * 4;
    float4 v = *(float4*)(out + idx);
    v.x = fmaf(sA[ch+0], v.x, sC[ch+0]);
    v.y = fmaf(sA[ch+1], v.y, sC[ch+1]);
    v.z = fmaf(sA[ch+2], v.z, sC[ch+2]);
    v.w = fmaf(sA[ch+3], v.w, sC[ch+3]);
    *(float4*)(out + idx) = v;
}

extern "C" void kernel_launch(void* const* d_in, const int* in_sizes, int n_in,
                              void* d_out, int out_size, void* d_ws, size_t ws_size,
                              hipStream_t stream) {
    const float* x        = (const float*)d_in[0];
    const int*   ei       = (const int*)d_in[1];
    const float* Wl       = (const float*)d_in[2];
    const float* bl       = (const float*)d_in[3];
    const float* Wr       = (const float*)d_in[4];
    const float* br       = (const float*)d_in[5];
    const float* att      = (const float*)d_in[6];
    const float* bias_gat = (const float*)d_in[7];
    const float* gamma1   = (const float*)d_in[8];
    const float* beta1    = (const float*)d_in[9];
    const float* W1       = (const float*)d_in[10];
    const float* b1       = (const float*)d_in[11];
    const float* W2       = (const float*)d_in[12];
    const float* b2       = (const float*)d_in[13];
    const float* gamma2   = (const float*)d_in[14];
    const float* beta2    = (const float*)d_in[15];
    float* out = (float*)d_out;

    char* ws = (char*)d_ws;
    unsigned short* xlb = (unsigned short*)ws;                         // N*256 bf16
    unsigned short* xrb = xlb + (size_t)N_NODES * HC;                  // N*256 bf16
    float* y1    = (float*)(xrb + (size_t)N_NODES * HC);               // N*64 f32
    int*   perm  = (int*)(y1 + (size_t)N_NODES * HIDDEN);              // N*MAXDEG <- zeroed by k_wprep
    int*   cursor= perm + (size_t)N_NODES * MAXDEG;                    // N    <- zeroed by k_wprep
    float* stats = (float*)(cursor + N_NODES);                         // 2048 <- zeroed by k_wprep
    unsigned short* W1tb  = (unsigned short*)(stats + 2048);           // 64*256
    unsigned short* W2tb  = W1tb + 16384;                              // 256*64
    unsigned short* Wlrtb = W2tb + 16384;                              // 2 * 64*256

    // stats layout: [0:512) gsum1, [512:1024) gsq1, [1024:1536) gsum2, [1536:2048) gsq2 (8 replicas x 64)
    k_wprep<<<256, 256, 0, stream>>>(W1, W2, Wl, Wr, W1tb, W2tb, Wlrtb, cursor, perm);
    k_prep <<<NB_LIN + NB_FILL, 256, 0, stream>>>(x, Wlrtb, bl, br, xlb, xrb, ei, cursor, perm);
    k_gat  <<<N_NODES / 8, 256, 0, stream>>>(xlb, xrb, att, perm, cursor, x, bias_gat, y1,
                                             stats + 0, stats + 512);
    k_ffn  <<<(N_NODES + 63) / 64, 256, 0, stream>>>(y1, stats + 0, stats + 512, gamma1, beta1,
                                                     W1tb, b1, W2tb, b2, out,
                                                     stats + 1024, stats + 1536);
    k_apply<<<N_NODES * HIDDEN / 1024, 256, 0, stream>>>(out, stats + 1024, stats + 1536, gamma2, beta2);
}